// Round 1
// baseline (19524.460 us; speedup 1.0000x reference)
//
#include <hip/hip_runtime.h>
#include <hip/hip_bf16.h>
#include <cstddef>

// Problem constants
#define NL   4
#define BB   16     // batch
#define TT   128    // seq len (S == T)
#define HH   512    // hidden == embed
#define G4   2048   // 4*H
#define BT   2048   // B*T tokens
#define VV   32000  // vocab

// ---------------- embedding gather ----------------
// one block per token, 128 threads x float4 = 512 floats
__global__ __launch_bounds__(128) void embed_kern(const int* __restrict__ idx,
                                                  const float* __restrict__ emb,
                                                  float* __restrict__ out) {
  int tk = blockIdx.x;               // 0..BT-1
  int row = idx[tk];
  const float4* s = (const float4*)(emb + (size_t)row * HH);
  float4* d = (float4*)(out + (size_t)tk * HH);
  d[threadIdx.x] = s[threadIdx.x];
}

// ---------------- small utility kernels ----------------
__global__ __launch_bounds__(256) void zero_kern(float* __restrict__ p, int n) {
  int i = blockIdx.x * 256 + threadIdx.x;
  if (i < n) p[i] = 0.f;
}
__global__ __launch_bounds__(256) void copy_kern(float* __restrict__ d,
                                                 const float* __restrict__ s, int n) {
  int i = blockIdx.x * 256 + threadIdx.x;
  if (i < n) d[i] = s[i];
}

// ---------------- fp32 tiled GEMM: C[M,N] = A[M,K] @ B[N,K]^T + bias[N] ----------------
#define BM 128
#define BN 64
#define BK 16
__global__ __launch_bounds__(256) void gemm_bias_kern(
    const float* __restrict__ A, const float* __restrict__ B,
    const float* __restrict__ bias, float* __restrict__ C,
    int M, int N, int K)
{
  __shared__ float As[BK][BM];
  __shared__ float Bs[BK][BN];
  const int tid = threadIdx.x;
  const int m0 = blockIdx.y * BM;
  const int n0 = blockIdx.x * BN;
  const int ty = tid >> 4;   // 0..15 -> 8 rows each
  const int tx = tid & 15;   // 0..15 -> 4 cols each

  float acc[8][4];
#pragma unroll
  for (int i = 0; i < 8; ++i)
#pragma unroll
    for (int j = 0; j < 4; ++j) acc[i][j] = 0.f;

  for (int k0 = 0; k0 < K; k0 += BK) {
    // stage A tile (128x16) transposed into As[k][m]; 512 float4 loads, 2/thread
#pragma unroll
    for (int i = 0; i < 2; ++i) {
      int f = tid * 2 + i;            // 0..511
      int row = f >> 2;               // 0..127
      int k4 = (f & 3) * 4;           // 0,4,8,12
      float4 v = *(const float4*)(A + (size_t)(m0 + row) * K + k0 + k4);
      As[k4 + 0][row] = v.x;
      As[k4 + 1][row] = v.y;
      As[k4 + 2][row] = v.z;
      As[k4 + 3][row] = v.w;
    }
    // stage B tile (64x16) transposed into Bs[k][n]; 256 float4 loads, 1/thread
    {
      int row = tid >> 2;             // 0..63
      int k4 = (tid & 3) * 4;
      float4 v = *(const float4*)(B + (size_t)(n0 + row) * K + k0 + k4);
      Bs[k4 + 0][row] = v.x;
      Bs[k4 + 1][row] = v.y;
      Bs[k4 + 2][row] = v.z;
      Bs[k4 + 3][row] = v.w;
    }
    __syncthreads();
#pragma unroll
    for (int k = 0; k < BK; ++k) {
      float4 a0 = *(const float4*)&As[k][ty * 8];
      float4 a1 = *(const float4*)&As[k][ty * 8 + 4];
      float4 bv = *(const float4*)&Bs[k][tx * 4];
      float av[8] = {a0.x, a0.y, a0.z, a0.w, a1.x, a1.y, a1.z, a1.w};
      float bb[4] = {bv.x, bv.y, bv.z, bv.w};
#pragma unroll
      for (int i = 0; i < 8; ++i)
#pragma unroll
        for (int j = 0; j < 4; ++j) acc[i][j] += av[i] * bb[j];
    }
    __syncthreads();
  }
#pragma unroll
  for (int i = 0; i < 8; ++i) {
    size_t row = (size_t)(m0 + ty * 8 + i);
#pragma unroll
    for (int j = 0; j < 4; ++j) {
      int col = n0 + tx * 4 + j;
      C[row * (size_t)N + col] = acc[i][j] + (bias ? bias[col] : 0.f);
    }
  }
}

// ---------------- LSTM cell step ----------------
// gates[b, col] = xW[b*T + t, col] + sum_k h_in[b,k] * Whh[col,k]
// block bk owns hidden units j0..j0+3 (16 gate cols), 256 threads = 16 b x 16 cols
#define HPAD 516   // 512 + 4 -> bank-conflict-free float4 rows
__global__ __launch_bounds__(256) void lstm_step_kern(
    const float* __restrict__ xW,     // [BT, G4] (bias already folded in)
    const float* __restrict__ Whh,    // [G4, HH]
    const float* __restrict__ h_in,   // [BB, HH]
    float* __restrict__ h_out,        // [BB, HH]
    float* __restrict__ c,            // [BB, HH] in-place
    float* __restrict__ hs_out,       // [BB, TT, HH]
    int t)
{
  __shared__ float sh[BB * HPAD];
  __shared__ float gsm[BB][17];
  const int tid = threadIdx.x;
  const int j0 = blockIdx.x * 4;

  // stage h_in (16x512) into LDS, 2048 float4 / 256 threads = 8 each
#pragma unroll
  for (int i = 0; i < 8; ++i) {
    int f = tid + 256 * i;            // float4 index 0..2047
    int row = f >> 7;                 // 0..15
    int c4 = (f & 127) * 4;
    float4 v = *(const float4*)(h_in + (size_t)row * HH + c4);
    *(float4*)&sh[row * HPAD + c4] = v;
  }
  __syncthreads();

  const int b = tid >> 4;             // 0..15
  const int cl = tid & 15;            // 0..15 : g = cl>>2, u = cl&3
  const int g = cl >> 2;
  const int u = cl & 3;
  const int gcol = g * HH + j0 + u;

  const float* __restrict__ wrow = Whh + (size_t)gcol * HH;
  const float* __restrict__ hrow = sh + b * HPAD;

  float acc = xW[(size_t)(b * TT + t) * G4 + gcol];
  float acc2 = 0.f;
#pragma unroll 8
  for (int k = 0; k < HH; k += 8) {
    float4 w0 = *(const float4*)(wrow + k);
    float4 h0 = *(const float4*)(hrow + k);
    float4 w1 = *(const float4*)(wrow + k + 4);
    float4 h1 = *(const float4*)(hrow + k + 4);
    acc  += w0.x * h0.x + w0.y * h0.y + w0.z * h0.z + w0.w * h0.w;
    acc2 += w1.x * h1.x + w1.y * h1.y + w1.z * h1.z + w1.w * h1.w;
  }
  gsm[b][cl] = acc + acc2;
  __syncthreads();

  if (cl < 4) {
    int j = j0 + cl;
    float iv = gsm[b][cl];
    float fv = gsm[b][4 + cl];
    float gv = gsm[b][8 + cl];
    float ov = gsm[b][12 + cl];
    float cv = c[b * HH + j];
    float si = 1.f / (1.f + expf(-iv));
    float sf = 1.f / (1.f + expf(-fv));
    float so = 1.f / (1.f + expf(-ov));
    float tg = tanhf(gv);
    float cn = sf * cv + si * tg;
    float hn = so * tanhf(cn);
    c[b * HH + j] = cn;
    h_out[b * HH + j] = hn;
    hs_out[(size_t)(b * TT + t) * HH + j] = hn;
  }
}

// ---------------- host side ----------------
extern "C" void kernel_launch(void* const* d_in, const int* in_sizes, int n_in,
                              void* d_out, int out_size, void* d_ws, size_t ws_size,
                              hipStream_t stream) {
  const int*   src     = (const int*)d_in[0];
  const int*   tgt     = (const int*)d_in[1];
  const float* src_emb = (const float*)d_in[2];
  const float* tgt_emb = (const float*)d_in[3];
  const float* enc_Wih = (const float*)d_in[4];
  const float* enc_Whh = (const float*)d_in[5];
  const float* enc_b   = (const float*)d_in[6];
  const float* dec_Wih = (const float*)d_in[7];
  const float* dec_Whh = (const float*)d_in[8];
  const float* dec_b   = (const float*)d_in[9];
  const float* fc_W    = (const float*)d_in[10];
  const float* fc_b    = (const float*)d_in[11];
  float* out = (float*)d_out;

  float* ws = (float*)d_ws;
  float* srcx  = ws;                 ws += (size_t)BT * HH;   // 1M
  float* tgtx  = ws;                 ws += (size_t)BT * HH;   // 1M
  float* hsA   = ws;                 ws += (size_t)BT * HH;   // 1M
  float* hsB   = ws;                 ws += (size_t)BT * HH;   // 1M
  float* xW    = ws;                 ws += (size_t)BT * G4;   // 4M
  float* hping = ws;                 ws += BB * HH;
  float* hpong = ws;                 ws += BB * HH;
  float* cbuf  = ws;                 ws += BB * HH;
  float* finh  = ws;                 ws += NL * BB * HH;
  float* finc  = ws;                 ws += NL * BB * HH;

  embed_kern<<<BT, 128, 0, stream>>>(src, src_emb, srcx);
  embed_kern<<<BT, 128, 0, stream>>>(tgt, tgt_emb, tgtx);

  const int stateN = BB * HH;                    // 8192
  const int stateGrid = (stateN + 255) / 256;

  const float* dec_out = nullptr;

  for (int stack = 0; stack < 2; ++stack) {
    const float* Wih  = stack ? dec_Wih : enc_Wih;
    const float* Whh  = stack ? dec_Whh : enc_Whh;
    const float* bia  = stack ? dec_b   : enc_b;
    const float* curX = stack ? tgtx    : srcx;

    for (int l = 0; l < NL; ++l) {
      float* hs_out = (l & 1) ? hsB : hsA;

      // input GEMM: xW = curX @ Wih[l]^T + b[l]
      {
        dim3 grid(G4 / BN, BT / BM);
        gemm_bias_kern<<<grid, 256, 0, stream>>>(
            curX, Wih + (size_t)l * G4 * HH, bia + (size_t)l * G4, xW,
            BT, G4, HH);
      }

      // init h, c
      if (stack == 0) {
        zero_kern<<<stateGrid, 256, 0, stream>>>(hping, stateN);
        zero_kern<<<stateGrid, 256, 0, stream>>>(cbuf, stateN);
      } else {
        copy_kern<<<stateGrid, 256, 0, stream>>>(hping, finh + (size_t)l * stateN, stateN);
        copy_kern<<<stateGrid, 256, 0, stream>>>(cbuf,  finc + (size_t)l * stateN, stateN);
      }

      // recurrence
      for (int t = 0; t < TT; ++t) {
        float* hin  = (t & 1) ? hpong : hping;
        float* hout = (t & 1) ? hping : hpong;
        lstm_step_kern<<<HH / 4, 256, 0, stream>>>(
            xW, Whh + (size_t)l * G4 * HH, hin, hout, cbuf, hs_out, t);
      }
      // final h is in hping (t=127 writes hping)

      if (stack == 0) {
        copy_kern<<<stateGrid, 256, 0, stream>>>(finh + (size_t)l * stateN, hping, stateN);
        copy_kern<<<stateGrid, 256, 0, stream>>>(finc + (size_t)l * stateN, cbuf, stateN);
      }

      curX = hs_out;
      if (stack == 1 && l == NL - 1) dec_out = hs_out;
    }
  }

  // final vocab projection: out = dec_out @ fc_W^T + fc_b  [2048, 32000]
  {
    dim3 grid(VV / BN, BT / BM);
    gemm_bias_kern<<<grid, 256, 0, stream>>>(dec_out, fc_W, fc_b, out, BT, VV, HH);
  }
}